// Round 6
// baseline (588.216 us; speedup 1.0000x reference)
//
#include <hip/hip_runtime.h>
#include <hip/hip_bf16.h>
#include <stdint.h>

#define NN 50000
#define NE 800000
#define IND 128
#define HID 256
#define MPAD 50048      // 391 * 128
#define NTILES_M 391
#define NBLK 49         // ceil(NN/1024)

typedef unsigned int uint32;
typedef unsigned short ushort_t;
typedef __attribute__((ext_vector_type(8))) short short8;
typedef __attribute__((ext_vector_type(4))) float f32x4;
typedef __attribute__((ext_vector_type(4))) unsigned int u32x4v;
typedef __attribute__((ext_vector_type(2))) unsigned int u32x2v;

typedef const __attribute__((address_space(1))) void* gptr_t;
typedef __attribute__((address_space(3))) void* lptr_t;

__device__ __forceinline__ ushort_t f2b(float f) {
  uint32 u = __float_as_uint(f);
  u = (u + 0x7fffu + ((u >> 16) & 1u)) >> 16;
  return (ushort_t)u;
}
__device__ __forceinline__ float blo(uint32 u) { return __uint_as_float(u << 16); }
__device__ __forceinline__ float bhi(uint32 u) { return __uint_as_float(u & 0xffff0000u); }
__device__ __forceinline__ uint32 pack2(float a, float b) {
  return (uint32)f2b(a) | ((uint32)f2b(b) << 16);
}

// ---------------- CSR build ----------------
__global__ void zero_k(int* __restrict__ p, int n) {
  int i = blockIdx.x * 256 + threadIdx.x;
  if (i < n) p[i] = 0;
}

__global__ void hist_k(const int* __restrict__ dst, int* __restrict__ cnt) {
  int e = blockIdx.x * 256 + threadIdx.x;
  if (e < NE) atomicAdd(&cnt[dst[e]], 1);
}

__global__ void bsum_k(const int* __restrict__ cnt, int* __restrict__ bsum) {
  __shared__ int ws[16];
  const int tid = threadIdx.x, ln = tid & 63, wv = tid >> 6;
  int i = blockIdx.x * 1024 + tid;
  int v = (i < NN) ? cnt[i] : 0;
#pragma unroll
  for (int d = 32; d; d >>= 1) v += __shfl_down(v, d, 64);
  if (ln == 0) ws[wv] = v;
  __syncthreads();
  if (tid < 16) {
    int s = ws[tid];
#pragma unroll
    for (int d = 8; d; d >>= 1) s += __shfl_down(s, d, 64);
    if (tid == 0) bsum[blockIdx.x] = s;
  }
}

__global__ void bscan_k(int* __restrict__ bsum, int* __restrict__ rp) {
  int tid = threadIdx.x;
  int v = (tid < NBLK) ? bsum[tid] : 0;
  int x = v;
#pragma unroll
  for (int d = 1; d < 64; d <<= 1) {
    int t = __shfl_up(x, d, 64);
    if (tid >= d) x += t;
  }
  if (tid < NBLK) bsum[tid] = x - v;
  if (tid == 0) rp[NN] = NE;
}

__global__ void scan2_k(const int* __restrict__ cnt, const int* __restrict__ bsum,
                        int* __restrict__ rp, int* __restrict__ cur) {
  __shared__ int ws[16];
  const int tid = threadIdx.x, ln = tid & 63, wv = tid >> 6;
  int i = blockIdx.x * 1024 + tid;
  int v = (i < NN) ? cnt[i] : 0;
  int x = v;
#pragma unroll
  for (int d = 1; d < 64; d <<= 1) {
    int t = __shfl_up(x, d, 64);
    if (ln >= d) x += t;
  }
  if (ln == 63) ws[wv] = x;
  __syncthreads();
  if (tid < 16) {
    int s = ws[tid];
#pragma unroll
    for (int d = 1; d < 16; d <<= 1) {
      int t = __shfl_up(s, d, 64);
      if (tid >= d) s += t;
    }
    ws[tid] = s;
  }
  __syncthreads();
  int excl = x - v + (wv ? ws[wv - 1] : 0) + bsum[blockIdx.x];
  if (i < NN) { rp[i] = excl; cur[i] = excl; }
}

__global__ void scatter_k(const int* __restrict__ src, const int* __restrict__ dst,
                          int* __restrict__ cur, int* __restrict__ esrc) {
  int e = blockIdx.x * 256 + threadIdx.x;
  if (e < NE) {
    int p = atomicAdd(&cur[dst[e]], 1);
    esrc[p] = src[e];
  }
}

// ---------------- weight / BN / input prep ----------------
__global__ void prepw_k(const float* __restrict__ w1_0, const float* __restrict__ w2_0,
                        const float* __restrict__ w1_r, const float* __restrict__ w2_r,
                        ushort_t* __restrict__ wt) {
  const int which = blockIdx.y;
  const int n = blockIdx.x, k = threadIdx.x;
  const float* w; ushort_t* o; int K = HID;
  switch (which) {
    case 0: w = w1_0; o = wt; K = IND; break;
    case 1: w = w2_0; o = wt + HID * IND; break;
    case 2: w = w1_r; o = wt + HID * IND + 1 * HID * HID; break;
    case 3: w = w2_r; o = wt + HID * IND + 2 * HID * HID; break;
    case 4: w = w1_r + HID * HID; o = wt + HID * IND + 3 * HID * HID; break;
    default: w = w2_r + HID * HID; o = wt + HID * IND + 4 * HID * HID; break;
  }
  if (k < K) o[n * K + k] = f2b(w[(size_t)k * HID + n]);
}

__global__ void prepbn_k(const float* b1_0, const float* b2_0, const float* g0,
                         const float* be0, const float* m0, const float* v0,
                         const float* b1_r, const float* b2_r, const float* g_r,
                         const float* be_r, const float* m_r, const float* v_r,
                         float* sc1, float* bi1, float* sc2, float* bi2) {
  int l = blockIdx.x, j = threadIdx.x;
  float b1, b2, g, be, m, v;
  if (l == 0) { b1 = b1_0[j]; b2 = b2_0[j]; g = g0[j]; be = be0[j]; m = m0[j]; v = v0[j]; }
  else { int o = (l - 1) * HID + j; b1 = b1_r[o]; b2 = b2_r[o]; g = g_r[o]; be = be_r[o]; m = m_r[o]; v = v_r[o]; }
  int o = l * HID + j;
  sc1[o] = 1.0f;
  bi1[o] = b1;
  float s = g * rsqrtf(v + 1e-5f);
  sc2[o] = s;
  bi2[o] = (b2 - m) * s + be;
}

// cast x (NN x 128 fp32) -> bf16
__global__ void x2b_k(const float* __restrict__ x, ushort_t* __restrict__ xb) {
  int i = blockIdx.x * 256 + threadIdx.x;
  const int n = NN * IND / 2;
  if (i < n) {
    float2 f = ((const float2*)x)[i];
    ((uint32*)xb)[i] = pack2(f.x, f.y);
  }
}

// zero row NN (the "zero row" used by predicated agg gathers) of xb, bufA, bufB
__global__ void zrows_k(ushort_t* xb, ushort_t* bufA, ushort_t* bufB) {
  int t = threadIdx.x;
  if (t < 64)  ((uint32*)(xb + (size_t)NN * IND))[t] = 0;     // 256 B
  if (t < 128) ((uint32*)(bufA + (size_t)NN * HID))[t] = 0;   // 512 B
  if (t < 128) ((uint32*)(bufB + (size_t)NN * HID))[t] = 0;   // 512 B
}

// ---------------- aggregation: z = h + sum_{j in N(i)} h_j ----------------
// Half-wave (32 lanes) per node. Depth-8 gather pipeline FORCED via inline asm:
// 8 x global_load_dwordx4 back-to-back, one s_waitcnt vmcnt(0). Outputs are
// EARLY-CLOBBER (=&v) so results can't alias pending address registers (R5 fault).
__global__ __launch_bounds__(256, 4) void agg256_k(
    const ushort_t* __restrict__ h, const int* __restrict__ rp,
    const int* __restrict__ esrc, ushort_t* __restrict__ z) {
  const int tid = threadIdx.x;
  const int half = tid >> 5;
  const int sl = tid & 31;
  const int node = blockIdx.x * 8 + half;   // grid covers exactly NN
  const uint32 slb = (uint32)sl * 16;
  const char* hb = (const char*)h;
  uint4 v = *(const uint4*)(hb + (size_t)node * 512 + slb);
  float a0 = blo(v.x), a1 = bhi(v.x), a2 = blo(v.y), a3 = bhi(v.y);
  float a4 = blo(v.z), a5 = bhi(v.z), a6 = blo(v.w), a7 = bhi(v.w);
  int e0 = rp[node], e1 = rp[node + 1];
  const uint32 zo = ((uint32)NN << 9) + slb;
  for (int e = e0; e < e1; e += 8) {
    uint32 off[8];
#pragma unroll
    for (int q = 0; q < 8; q++) {
      int idx = e + q;
      int s = esrc[idx];                     // esrc padded by 8 ints
      off[q] = (idx < e1) ? (((uint32)s << 9) + slb) : zo;
    }
    u32x4v u0, u1, u2, u3, u4, u5, u6, u7;
    asm volatile(
        "global_load_dwordx4 %0, %8, %16\n\t"
        "global_load_dwordx4 %1, %9, %16\n\t"
        "global_load_dwordx4 %2, %10, %16\n\t"
        "global_load_dwordx4 %3, %11, %16\n\t"
        "global_load_dwordx4 %4, %12, %16\n\t"
        "global_load_dwordx4 %5, %13, %16\n\t"
        "global_load_dwordx4 %6, %14, %16\n\t"
        "global_load_dwordx4 %7, %15, %16\n\t"
        "s_waitcnt vmcnt(0)"
        : "=&v"(u0), "=&v"(u1), "=&v"(u2), "=&v"(u3),
          "=&v"(u4), "=&v"(u5), "=&v"(u6), "=&v"(u7)
        : "v"(off[0]), "v"(off[1]), "v"(off[2]), "v"(off[3]),
          "v"(off[4]), "v"(off[5]), "v"(off[6]), "v"(off[7]),
          "s"(hb)
        : "memory");
    u32x4v uu[8] = {u0, u1, u2, u3, u4, u5, u6, u7};
#pragma unroll
    for (int q = 0; q < 8; q++) {
      a0 += blo(uu[q].x); a1 += bhi(uu[q].x); a2 += blo(uu[q].y); a3 += bhi(uu[q].y);
      a4 += blo(uu[q].z); a5 += bhi(uu[q].z); a6 += blo(uu[q].w); a7 += bhi(uu[q].w);
    }
  }
  uint4 o;
  o.x = pack2(a0, a1); o.y = pack2(a2, a3); o.z = pack2(a4, a5); o.w = pack2(a6, a7);
  *(uint4*)((char*)z + (size_t)node * 512 + slb) = o;
}

__global__ __launch_bounds__(256, 4) void agg128_k(
    const ushort_t* __restrict__ h, const int* __restrict__ rp,
    const int* __restrict__ esrc, ushort_t* __restrict__ z) {
  const int tid = threadIdx.x;
  const int half = tid >> 5;
  const int sl = tid & 31;
  const int node = blockIdx.x * 8 + half;
  const uint32 slb = (uint32)sl * 8;
  const char* hb = (const char*)h;
  uint2 v = *(const uint2*)(hb + (size_t)node * 256 + slb);
  float a0 = blo(v.x), a1 = bhi(v.x), a2 = blo(v.y), a3 = bhi(v.y);
  int e0 = rp[node], e1 = rp[node + 1];
  const uint32 zo = ((uint32)NN << 8) + slb;
  for (int e = e0; e < e1; e += 8) {
    uint32 off[8];
#pragma unroll
    for (int q = 0; q < 8; q++) {
      int idx = e + q;
      int s = esrc[idx];
      off[q] = (idx < e1) ? (((uint32)s << 8) + slb) : zo;
    }
    u32x2v u0, u1, u2, u3, u4, u5, u6, u7;
    asm volatile(
        "global_load_dwordx2 %0, %8, %16\n\t"
        "global_load_dwordx2 %1, %9, %16\n\t"
        "global_load_dwordx2 %2, %10, %16\n\t"
        "global_load_dwordx2 %3, %11, %16\n\t"
        "global_load_dwordx2 %4, %12, %16\n\t"
        "global_load_dwordx2 %5, %13, %16\n\t"
        "global_load_dwordx2 %6, %14, %16\n\t"
        "global_load_dwordx2 %7, %15, %16\n\t"
        "s_waitcnt vmcnt(0)"
        : "=&v"(u0), "=&v"(u1), "=&v"(u2), "=&v"(u3),
          "=&v"(u4), "=&v"(u5), "=&v"(u6), "=&v"(u7)
        : "v"(off[0]), "v"(off[1]), "v"(off[2]), "v"(off[3]),
          "v"(off[4]), "v"(off[5]), "v"(off[6]), "v"(off[7]),
          "s"(hb)
        : "memory");
    u32x2v uu[8] = {u0, u1, u2, u3, u4, u5, u6, u7};
#pragma unroll
    for (int q = 0; q < 8; q++) {
      a0 += blo(uu[q].x); a1 += bhi(uu[q].x); a2 += blo(uu[q].y); a3 += bhi(uu[q].y);
    }
  }
  uint2 o; o.x = pack2(a0, a1); o.y = pack2(a2, a3);
  *(uint2*)((char*)z + (size_t)node * 256 + slb) = o;
}

// ---------------- GEMM: C[m][n] = sum_k A[m][k] * Bt[n][k], + per-col scale/bias ----------------
__global__ __launch_bounds__(256) void gemm_k(
    const ushort_t* __restrict__ A, const ushort_t* __restrict__ Bt,
    const float* __restrict__ sc, const float* __restrict__ bi,
    void* __restrict__ out, int K, int lrelu, int f32out) {
  __shared__ ushort_t As[128 * 32];
  __shared__ ushort_t Bs[128 * 32];
  const int tid = threadIdx.x;
  const int lane = tid & 63;
  const int wid = tid >> 6;
  const int m0 = blockIdx.x * 128;
  const int n0 = blockIdx.y * 128;
  const int wm = (wid & 1) * 64;
  const int wn = (wid >> 1) * 64;
  const int srow = tid >> 2;
  const int sch = (tid & 3) * 8;
  const int fr = lane & 15;
  const int fk = (lane >> 4) * 8;

  f32x4 zero = {0.f, 0.f, 0.f, 0.f};
  f32x4 acc[4][4];
#pragma unroll
  for (int i = 0; i < 4; i++)
#pragma unroll
    for (int j = 0; j < 4; j++) acc[i][j] = zero;

  for (int kk = 0; kk < K; kk += 32) {
    const ushort_t* ga = A + (size_t)(m0 + srow) * K + kk + sch;
    const ushort_t* gb = Bt + (size_t)(n0 + srow) * K + kk + sch;
    ushort_t* la = As + srow * 32 + sch;
    ushort_t* lb = Bs + srow * 32 + sch;
    __builtin_amdgcn_global_load_lds((gptr_t)ga, (lptr_t)la, 16, 0, 0);
    __builtin_amdgcn_global_load_lds((gptr_t)(ga + (size_t)64 * K), (lptr_t)(la + 64 * 32), 16, 0, 0);
    __builtin_amdgcn_global_load_lds((gptr_t)gb, (lptr_t)lb, 16, 0, 0);
    __builtin_amdgcn_global_load_lds((gptr_t)(gb + (size_t)64 * K), (lptr_t)(lb + 64 * 32), 16, 0, 0);
    __syncthreads();

    short8 af[4], bfv[4];
#pragma unroll
    for (int i = 0; i < 4; i++)
      af[i] = *(const short8*)(As + (wm + i * 16 + fr) * 32 + fk);
#pragma unroll
    for (int j = 0; j < 4; j++)
      bfv[j] = *(const short8*)(Bs + (wn + j * 16 + fr) * 32 + fk);
#pragma unroll
    for (int i = 0; i < 4; i++)
#pragma unroll
      for (int j = 0; j < 4; j++)
        acc[i][j] = __builtin_amdgcn_mfma_f32_16x16x32_bf16(af[i], bfv[j], acc[i][j], 0, 0, 0);
    __syncthreads();
  }

  const int er = lane >> 4;
  const int ec = lane & 15;
#pragma unroll
  for (int j = 0; j < 4; j++) {
    int col = n0 + wn + j * 16 + ec;
    float s = sc[col], b = bi[col];
#pragma unroll
    for (int i = 0; i < 4; i++) {
      int row0 = m0 + wm + i * 16 + er * 4;
#pragma unroll
      for (int r = 0; r < 4; r++) {
        float v = acc[i][j][r] * s + b;
        if (lrelu) v = (v > 0.f) ? v : 0.01f * v;
        int row = row0 + r;
        if (row < NN) {   // keep zero row NN (and pad) untouched
          if (f32out) ((float*)out)[(size_t)row * HID + col] = v;
          else        ((ushort_t*)out)[(size_t)row * HID + col] = f2b(v);
        }
      }
    }
  }
}

extern "C" void kernel_launch(void* const* d_in, const int* in_sizes, int n_in,
                              void* d_out, int out_size, void* d_ws, size_t ws_size,
                              hipStream_t stream) {
  const float* x    = (const float*)d_in[0];
  const int*   src  = (const int*)d_in[1];
  const int*   dst  = (const int*)d_in[2];
  const float* w1_0 = (const float*)d_in[3];
  const float* b1_0 = (const float*)d_in[4];
  const float* w2_0 = (const float*)d_in[5];
  const float* b2_0 = (const float*)d_in[6];
  const float* g0   = (const float*)d_in[7];
  const float* be0  = (const float*)d_in[8];
  const float* m0   = (const float*)d_in[9];
  const float* v0   = (const float*)d_in[10];
  const float* w1_r = (const float*)d_in[11];
  const float* b1_r = (const float*)d_in[12];
  const float* w2_r = (const float*)d_in[13];
  const float* b2_r = (const float*)d_in[14];
  const float* g_r  = (const float*)d_in[15];
  const float* be_r = (const float*)d_in[16];
  const float* m_r  = (const float*)d_in[17];
  const float* v_r  = (const float*)d_in[18];

  char* ws = (char*)d_ws;
  size_t off = 0;
  auto alloc = [&](size_t bytes) {
    void* p = ws + off;
    off = (off + bytes + 255) & ~(size_t)255;
    return p;
  };
  ushort_t* bufA  = (ushort_t*)alloc((size_t)MPAD * HID * 2);
  ushort_t* bufB  = (ushort_t*)alloc((size_t)MPAD * HID * 2);
  ushort_t* xb    = (ushort_t*)alloc((size_t)(NN + 1) * IND * 2);  // +1 zero row
  int*      rp    = (int*)alloc((NN + 1) * sizeof(int));
  int*      cur   = (int*)alloc(NN * sizeof(int));
  int*      bsum  = (int*)alloc(NBLK * sizeof(int));
  int*      esrc  = (int*)alloc((size_t)(NE + 8) * sizeof(int));   // +8 pad
  ushort_t* wt    = (ushort_t*)alloc(((size_t)HID * IND + 5 * (size_t)HID * HID) * 2);
  float*    sc1   = (float*)alloc(3 * HID * sizeof(float));
  float*    bi1   = (float*)alloc(3 * HID * sizeof(float));
  float*    sc2   = (float*)alloc(3 * HID * sizeof(float));
  float*    bi2   = (float*)alloc(3 * HID * sizeof(float));
  (void)ws_size; (void)in_sizes; (void)n_in; (void)out_size;

  ushort_t* w1_0t = wt;
  ushort_t* w2_0t = wt + HID * IND;
  ushort_t* w1r0t = wt + HID * IND + 1 * HID * HID;
  ushort_t* w2r0t = wt + HID * IND + 2 * HID * HID;
  ushort_t* w1r1t = wt + HID * IND + 3 * HID * HID;
  ushort_t* w2r1t = wt + HID * IND + 4 * HID * HID;

  // CSR build
  zero_k<<<(NN + 255) / 256, 256, 0, stream>>>(cur, NN);
  hist_k<<<(NE + 255) / 256, 256, 0, stream>>>(dst, cur);
  bsum_k<<<NBLK, 1024, 0, stream>>>(cur, bsum);
  bscan_k<<<1, 64, 0, stream>>>(bsum, rp);
  scan2_k<<<NBLK, 1024, 0, stream>>>(cur, bsum, rp, cur);
  scatter_k<<<(NE + 255) / 256, 256, 0, stream>>>(src, dst, cur, esrc);

  // weight/BN/input prep
  prepw_k<<<dim3(HID, 6), 256, 0, stream>>>(w1_0, w2_0, w1_r, w2_r, wt);
  prepbn_k<<<3, 256, 0, stream>>>(b1_0, b2_0, g0, be0, m0, v0,
                                  b1_r, b2_r, g_r, be_r, m_r, v_r,
                                  sc1, bi1, sc2, bi2);
  x2b_k<<<(NN * IND / 2 + 255) / 256, 256, 0, stream>>>(x, xb);
  zrows_k<<<1, 256, 0, stream>>>(xb, bufA, bufB);

  dim3 gg(NTILES_M, 2);
  // layer 0
  agg128_k<<<NN / 8, 256, 0, stream>>>(xb, rp, esrc, bufA);
  gemm_k<<<gg, 256, 0, stream>>>(bufA, w1_0t, sc1, bi1, bufB, IND, 1, 0);
  gemm_k<<<gg, 256, 0, stream>>>(bufB, w2_0t, sc2, bi2, bufA, HID, 1, 0);
  // layer 1
  agg256_k<<<NN / 8, 256, 0, stream>>>(bufA, rp, esrc, bufB);
  gemm_k<<<gg, 256, 0, stream>>>(bufB, w1r0t, sc1 + HID, bi1 + HID, bufA, HID, 1, 0);
  gemm_k<<<gg, 256, 0, stream>>>(bufA, w2r0t, sc2 + HID, bi2 + HID, bufB, HID, 1, 0);
  // layer 2
  agg256_k<<<NN / 8, 256, 0, stream>>>(bufB, rp, esrc, bufA);
  gemm_k<<<gg, 256, 0, stream>>>(bufA, w1r1t, sc1 + 2 * HID, bi1 + 2 * HID, bufB, HID, 1, 0);
  gemm_k<<<gg, 256, 0, stream>>>(bufB, w2r1t, sc2 + 2 * HID, bi2 + 2 * HID, d_out, HID, 0, 1);
}

// Round 7
// 496.253 us; speedup vs baseline: 1.1853x; 1.1853x over previous
//
#include <hip/hip_runtime.h>
#include <hip/hip_bf16.h>
#include <stdint.h>

#define NN 50000
#define NE 800000
#define IND 128
#define HID 256
#define MPAD 50048      // 782 * 64
#define NBLK 49         // ceil(NN/1024)

typedef unsigned int uint32;
typedef unsigned short ushort_t;
typedef __attribute__((ext_vector_type(8))) short short8;
typedef __attribute__((ext_vector_type(4))) float f32x4;

typedef const __attribute__((address_space(1))) void* gptr_t;
typedef __attribute__((address_space(3))) void* lptr_t;

__device__ __forceinline__ ushort_t f2b(float f) {
  uint32 u = __float_as_uint(f);
  u = (u + 0x7fffu + ((u >> 16) & 1u)) >> 16;
  return (ushort_t)u;
}
__device__ __forceinline__ float blo(uint32 u) { return __uint_as_float(u << 16); }
__device__ __forceinline__ float bhi(uint32 u) { return __uint_as_float(u & 0xffff0000u); }
__device__ __forceinline__ uint32 pack2(float a, float b) {
  return (uint32)f2b(a) | ((uint32)f2b(b) << 16);
}

// ---------------- CSR build ----------------
__global__ void zero_k(int* __restrict__ p, int n) {
  int i = blockIdx.x * 256 + threadIdx.x;
  if (i < n) p[i] = 0;
}

__global__ void hist_k(const int* __restrict__ dst, int* __restrict__ cnt) {
  int e = blockIdx.x * 256 + threadIdx.x;
  if (e < NE) atomicAdd(&cnt[dst[e]], 1);
}

__global__ void bsum_k(const int* __restrict__ cnt, int* __restrict__ bsum) {
  __shared__ int ws[16];
  const int tid = threadIdx.x, ln = tid & 63, wv = tid >> 6;
  int i = blockIdx.x * 1024 + tid;
  int v = (i < NN) ? cnt[i] : 0;
#pragma unroll
  for (int d = 32; d; d >>= 1) v += __shfl_down(v, d, 64);
  if (ln == 0) ws[wv] = v;
  __syncthreads();
  if (tid < 16) {
    int s = ws[tid];
#pragma unroll
    for (int d = 8; d; d >>= 1) s += __shfl_down(s, d, 64);
    if (tid == 0) bsum[blockIdx.x] = s;
  }
}

__global__ void bscan_k(int* __restrict__ bsum, int* __restrict__ rp) {
  int tid = threadIdx.x;
  int v = (tid < NBLK) ? bsum[tid] : 0;
  int x = v;
#pragma unroll
  for (int d = 1; d < 64; d <<= 1) {
    int t = __shfl_up(x, d, 64);
    if (tid >= d) x += t;
  }
  if (tid < NBLK) bsum[tid] = x - v;
  if (tid == 0) rp[NN] = NE;
}

__global__ void scan2_k(const int* __restrict__ cnt, const int* __restrict__ bsum,
                        int* __restrict__ rp, int* __restrict__ cur) {
  __shared__ int ws[16];
  const int tid = threadIdx.x, ln = tid & 63, wv = tid >> 6;
  int i = blockIdx.x * 1024 + tid;
  int v = (i < NN) ? cnt[i] : 0;
  int x = v;
#pragma unroll
  for (int d = 1; d < 64; d <<= 1) {
    int t = __shfl_up(x, d, 64);
    if (ln >= d) x += t;
  }
  if (ln == 63) ws[wv] = x;
  __syncthreads();
  if (tid < 16) {
    int s = ws[tid];
#pragma unroll
    for (int d = 1; d < 16; d <<= 1) {
      int t = __shfl_up(s, d, 64);
      if (tid >= d) s += t;
    }
    ws[tid] = s;
  }
  __syncthreads();
  int excl = x - v + (wv ? ws[wv - 1] : 0) + bsum[blockIdx.x];
  if (i < NN) { rp[i] = excl; cur[i] = excl; }
}

__global__ void scatter_k(const int* __restrict__ src, const int* __restrict__ dst,
                          int* __restrict__ cur, int* __restrict__ esrc) {
  int e = blockIdx.x * 256 + threadIdx.x;
  if (e < NE) {
    int p = atomicAdd(&cur[dst[e]], 1);
    esrc[p] = src[e];
  }
}

// ---------------- prep: weights (6 transposes) + BN folding, one launch ----------------
__global__ void prep_k(const float* __restrict__ w1_0, const float* __restrict__ w2_0,
                       const float* __restrict__ w1_r, const float* __restrict__ w2_r,
                       const float* b1_0, const float* b2_0, const float* g0,
                       const float* be0, const float* m0, const float* v0,
                       const float* b1_r, const float* b2_r, const float* g_r,
                       const float* be_r, const float* m_r, const float* v_r,
                       ushort_t* __restrict__ wt,
                       float* bi1, float* sc2, float* bi2) {
  const int which = blockIdx.y;
  if (which < 6) {
    const int n = blockIdx.x, k = threadIdx.x;
    const float* w; ushort_t* o; int K = HID;
    switch (which) {
      case 0: w = w1_0; o = wt; K = IND; break;
      case 1: w = w2_0; o = wt + HID * IND; break;
      case 2: w = w1_r; o = wt + HID * IND + 1 * HID * HID; break;
      case 3: w = w2_r; o = wt + HID * IND + 2 * HID * HID; break;
      case 4: w = w1_r + HID * HID; o = wt + HID * IND + 3 * HID * HID; break;
      default: w = w2_r + HID * HID; o = wt + HID * IND + 4 * HID * HID; break;
    }
    if (k < K) o[n * K + k] = f2b(w[(size_t)k * HID + n]);
  } else {
    const int l = blockIdx.x;
    if (l >= 3) return;
    const int j = threadIdx.x;
    float b1, b2, g, be, m, v;
    if (l == 0) { b1 = b1_0[j]; b2 = b2_0[j]; g = g0[j]; be = be0[j]; m = m0[j]; v = v0[j]; }
    else { int o = (l - 1) * HID + j; b1 = b1_r[o]; b2 = b2_r[o]; g = g_r[o]; be = be_r[o]; m = m_r[o]; v = v_r[o]; }
    int o = l * HID + j;
    bi1[o] = b1;
    float s = g * rsqrtf(v + 1e-5f);
    sc2[o] = s;
    bi2[o] = (b2 - m) * s + be;
  }
}

// cast x (NN x 128 fp32) -> bf16
__global__ void x2b_k(const float* __restrict__ x, ushort_t* __restrict__ xb) {
  int i = blockIdx.x * 256 + threadIdx.x;
  const int n = NN * IND / 2;
  if (i < n) {
    float2 f = ((const float2*)x)[i];
    ((uint32*)xb)[i] = pack2(f.x, f.y);
  }
}

// ---------------- aggregation (R2-proven structure): z = h + sum h_j ----------------
// 256-dim bf16: wave per node, lane = uint2 (4 dims), 8-edge unroll + remainder.
__global__ void agg256_k(const ushort_t* __restrict__ h, const int* __restrict__ rp,
                         const int* __restrict__ esrc, ushort_t* __restrict__ z) {
  int wid = threadIdx.x >> 6, lane = threadIdx.x & 63;
  int node = blockIdx.x * 4 + wid;
  if (node >= NN) return;
  const uint2* hp = (const uint2*)h;
  uint2 v = hp[(size_t)node * 64 + lane];
  float a0 = blo(v.x), a1 = bhi(v.x), a2 = blo(v.y), a3 = bhi(v.y);
  int e0 = rp[node], e1 = rp[node + 1];
  int e = e0;
  for (; e + 8 <= e1; e += 8) {
    int s[8];
#pragma unroll
    for (int q = 0; q < 8; q++) s[q] = esrc[e + q];
    uint2 u[8];
#pragma unroll
    for (int q = 0; q < 8; q++) u[q] = hp[(size_t)s[q] * 64 + lane];
#pragma unroll
    for (int q = 0; q < 8; q++) {
      a0 += blo(u[q].x); a1 += bhi(u[q].x); a2 += blo(u[q].y); a3 += bhi(u[q].y);
    }
  }
  for (; e < e1; e++) {
    int s = esrc[e];
    uint2 u = hp[(size_t)s * 64 + lane];
    a0 += blo(u.x); a1 += bhi(u.x); a2 += blo(u.y); a3 += bhi(u.y);
  }
  uint2 o; o.x = pack2(a0, a1); o.y = pack2(a2, a3);
  ((uint2*)z)[(size_t)node * 64 + lane] = o;
}

// 128-dim bf16: wave per node, lane = uint32 (2 dims).
__global__ void agg128_k(const ushort_t* __restrict__ h, const int* __restrict__ rp,
                         const int* __restrict__ esrc, ushort_t* __restrict__ z) {
  int wid = threadIdx.x >> 6, lane = threadIdx.x & 63;
  int node = blockIdx.x * 4 + wid;
  if (node >= NN) return;
  const uint32* hp = (const uint32*)h;
  uint32 v = hp[(size_t)node * 64 + lane];
  float a0 = blo(v), a1 = bhi(v);
  int e0 = rp[node], e1 = rp[node + 1];
  int e = e0;
  for (; e + 8 <= e1; e += 8) {
    int s[8];
#pragma unroll
    for (int q = 0; q < 8; q++) s[q] = esrc[e + q];
    uint32 u[8];
#pragma unroll
    for (int q = 0; q < 8; q++) u[q] = hp[(size_t)s[q] * 64 + lane];
#pragma unroll
    for (int q = 0; q < 8; q++) { a0 += blo(u[q]); a1 += bhi(u[q]); }
  }
  for (; e < e1; e++) {
    int s = esrc[e];
    uint32 u = hp[(size_t)s * 64 + lane];
    a0 += blo(u); a1 += bhi(u);
  }
  ((uint32*)z)[(size_t)node * 64 + lane] = pack2(a0, a1);
}

// ---------------- fused MLP: out = BN(lrelu(Z W1 + b1) W2 + b2) [opt lrelu] -----------
// 64-row x 256-col tile per block (grid 782), 4 waves, wave w -> cols w*64..+63.
// Phase 1: C1 = lrelu(Z*W1 + b1) -> LDS (64x264 bf16, padded).
// Phase 2: C2 = C1*W2, folded BN via sc2/bi2, optional lrelu, store.
__global__ __launch_bounds__(256, 2) void fgemm_k(
    const ushort_t* __restrict__ A, const ushort_t* __restrict__ B1t,
    const ushort_t* __restrict__ B2t, const float* __restrict__ bi1,
    const float* __restrict__ sc2, const float* __restrict__ bi2,
    void* __restrict__ out, int K1, int lrelu2, int f32out) {
  __shared__ ushort_t As[64 * 32];     // 4 KB
  __shared__ ushort_t Bs[256 * 32];    // 16 KB
  __shared__ ushort_t C1s[64 * 264];   // 33 KB, stride 264 -> 2-way-free b128 reads
  const int tid = threadIdx.x;
  const int lane = tid & 63;
  const int wid = tid >> 6;
  const int m0 = blockIdx.x * 64;
  const int srow = tid >> 2;           // 0..63
  const int sch = (tid & 3) * 8;       // bf16 offset within 32-wide k-chunk
  const int fr = lane & 15;
  const int fk = (lane >> 4) * 8;
  const int er = lane >> 4;
  const int ec = lane & 15;

  f32x4 zero = {0.f, 0.f, 0.f, 0.f};
  f32x4 acc[4][4];
#pragma unroll
  for (int i = 0; i < 4; i++)
#pragma unroll
    for (int j = 0; j < 4; j++) acc[i][j] = zero;

  // ---- phase 1: Z (64 x K1) * W1 (K1 x 256) ----
  for (int kk = 0; kk < K1; kk += 32) {
    __builtin_amdgcn_global_load_lds((gptr_t)(A + (size_t)(m0 + srow) * K1 + kk + sch),
                                     (lptr_t)(As + srow * 32 + sch), 16, 0, 0);
#pragma unroll
    for (int p = 0; p < 4; p++)
      __builtin_amdgcn_global_load_lds(
          (gptr_t)(B1t + (size_t)(p * 64 + srow) * K1 + kk + sch),
          (lptr_t)(Bs + (p * 64 + srow) * 32 + sch), 16, 0, 0);
    __syncthreads();
    short8 af[4], bfv[4];
#pragma unroll
    for (int i = 0; i < 4; i++)
      af[i] = *(const short8*)(As + (i * 16 + fr) * 32 + fk);
#pragma unroll
    for (int j = 0; j < 4; j++)
      bfv[j] = *(const short8*)(Bs + (wid * 64 + j * 16 + fr) * 32 + fk);
#pragma unroll
    for (int i = 0; i < 4; i++)
#pragma unroll
      for (int j = 0; j < 4; j++)
        acc[i][j] = __builtin_amdgcn_mfma_f32_16x16x32_bf16(af[i], bfv[j], acc[i][j], 0, 0, 0);
    __syncthreads();
  }

  // C1 = lrelu(acc + b1) -> LDS
#pragma unroll
  for (int j = 0; j < 4; j++) {
    int col = wid * 64 + j * 16 + ec;
    float b = bi1[col];
#pragma unroll
    for (int i = 0; i < 4; i++) {
#pragma unroll
      for (int r = 0; r < 4; r++) {
        int row = i * 16 + er * 4 + r;
        float v = acc[i][j][r] + b;
        v = (v > 0.f) ? v : 0.01f * v;
        C1s[row * 264 + col] = f2b(v);
      }
    }
  }
  __syncthreads();

  // ---- phase 2: C1 (64 x 256) * W2 (256 x 256) ----
  f32x4 acc2[4][4];
#pragma unroll
  for (int i = 0; i < 4; i++)
#pragma unroll
    for (int j = 0; j < 4; j++) acc2[i][j] = zero;

  for (int kk = 0; kk < HID; kk += 32) {
#pragma unroll
    for (int p = 0; p < 4; p++)
      __builtin_amdgcn_global_load_lds(
          (gptr_t)(B2t + (size_t)(p * 64 + srow) * HID + kk + sch),
          (lptr_t)(Bs + (p * 64 + srow) * 32 + sch), 16, 0, 0);
    __syncthreads();
    short8 af[4], bfv[4];
#pragma unroll
    for (int i = 0; i < 4; i++)
      af[i] = *(const short8*)(C1s + (i * 16 + fr) * 264 + kk + fk);
#pragma unroll
    for (int j = 0; j < 4; j++)
      bfv[j] = *(const short8*)(Bs + (wid * 64 + j * 16 + fr) * 32 + fk);
#pragma unroll
    for (int i = 0; i < 4; i++)
#pragma unroll
      for (int j = 0; j < 4; j++)
        acc2[i][j] = __builtin_amdgcn_mfma_f32_16x16x32_bf16(af[i], bfv[j], acc2[i][j], 0, 0, 0);
    __syncthreads();
  }

  // epilogue: BN fold (+opt lrelu), store
#pragma unroll
  for (int j = 0; j < 4; j++) {
    int col = wid * 64 + j * 16 + ec;
    float s = sc2[col], b = bi2[col];
#pragma unroll
    for (int i = 0; i < 4; i++) {
#pragma unroll
      for (int r = 0; r < 4; r++) {
        int row = m0 + i * 16 + er * 4 + r;
        float v = acc2[i][j][r] * s + b;
        if (lrelu2) v = (v > 0.f) ? v : 0.01f * v;
        if (row < NN) {
          if (f32out) ((float*)out)[(size_t)row * HID + col] = v;
          else        ((ushort_t*)out)[(size_t)row * HID + col] = f2b(v);
        }
      }
    }
  }
}

extern "C" void kernel_launch(void* const* d_in, const int* in_sizes, int n_in,
                              void* d_out, int out_size, void* d_ws, size_t ws_size,
                              hipStream_t stream) {
  const float* x    = (const float*)d_in[0];
  const int*   src  = (const int*)d_in[1];
  const int*   dst  = (const int*)d_in[2];
  const float* w1_0 = (const float*)d_in[3];
  const float* b1_0 = (const float*)d_in[4];
  const float* w2_0 = (const float*)d_in[5];
  const float* b2_0 = (const float*)d_in[6];
  const float* g0   = (const float*)d_in[7];
  const float* be0  = (const float*)d_in[8];
  const float* m0   = (const float*)d_in[9];
  const float* v0   = (const float*)d_in[10];
  const float* w1_r = (const float*)d_in[11];
  const float* b1_r = (const float*)d_in[12];
  const float* w2_r = (const float*)d_in[13];
  const float* b2_r = (const float*)d_in[14];
  const float* g_r  = (const float*)d_in[15];
  const float* be_r = (const float*)d_in[16];
  const float* m_r  = (const float*)d_in[17];
  const float* v_r  = (const float*)d_in[18];

  char* ws = (char*)d_ws;
  size_t off = 0;
  auto alloc = [&](size_t bytes) {
    void* p = ws + off;
    off = (off + bytes + 255) & ~(size_t)255;
    return p;
  };
  ushort_t* bufA  = (ushort_t*)alloc((size_t)MPAD * HID * 2);
  ushort_t* bufB  = (ushort_t*)alloc((size_t)MPAD * HID * 2);
  ushort_t* xb    = (ushort_t*)alloc((size_t)MPAD * IND * 2);
  int*      rp    = (int*)alloc((NN + 1) * sizeof(int));
  int*      cur   = (int*)alloc(NN * sizeof(int));
  int*      bsum  = (int*)alloc(NBLK * sizeof(int));
  int*      esrc  = (int*)alloc((size_t)NE * sizeof(int));
  ushort_t* wt    = (ushort_t*)alloc(((size_t)HID * IND + 5 * (size_t)HID * HID) * 2);
  float*    bi1   = (float*)alloc(3 * HID * sizeof(float));
  float*    sc2   = (float*)alloc(3 * HID * sizeof(float));
  float*    bi2   = (float*)alloc(3 * HID * sizeof(float));
  (void)ws_size; (void)in_sizes; (void)n_in; (void)out_size;

  ushort_t* w1_0t = wt;
  ushort_t* w2_0t = wt + HID * IND;
  ushort_t* w1r0t = wt + HID * IND + 1 * HID * HID;
  ushort_t* w2r0t = wt + HID * IND + 2 * HID * HID;
  ushort_t* w1r1t = wt + HID * IND + 3 * HID * HID;
  ushort_t* w2r1t = wt + HID * IND + 4 * HID * HID;

  // CSR build
  zero_k<<<(NN + 255) / 256, 256, 0, stream>>>(cur, NN);
  hist_k<<<(NE + 255) / 256, 256, 0, stream>>>(dst, cur);
  bsum_k<<<NBLK, 1024, 0, stream>>>(cur, bsum);
  bscan_k<<<1, 64, 0, stream>>>(bsum, rp);
  scan2_k<<<NBLK, 1024, 0, stream>>>(cur, bsum, rp, cur);
  scatter_k<<<(NE + 255) / 256, 256, 0, stream>>>(src, dst, cur, esrc);

  // weight/BN/input prep
  prep_k<<<dim3(HID, 7), 256, 0, stream>>>(w1_0, w2_0, w1_r, w2_r,
                                           b1_0, b2_0, g0, be0, m0, v0,
                                           b1_r, b2_r, g_r, be_r, m_r, v_r,
                                           wt, bi1, sc2, bi2);
  x2b_k<<<(NN * IND / 2 + 255) / 256, 256, 0, stream>>>(x, xb);

  const int GG = MPAD / 64;  // 782
  // layer 0
  agg128_k<<<NN / 4, 256, 0, stream>>>(xb, rp, esrc, bufA);
  fgemm_k<<<GG, 256, 0, stream>>>(bufA, w1_0t, w2_0t, bi1, sc2, bi2, bufB, IND, 1, 0);
  // layer 1
  agg256_k<<<NN / 4, 256, 0, stream>>>(bufB, rp, esrc, bufA);
  fgemm_k<<<GG, 256, 0, stream>>>(bufA, w1r0t, w2r0t, bi1 + HID, sc2 + HID, bi2 + HID, bufB, HID, 1, 0);
  // layer 2
  agg256_k<<<NN / 4, 256, 0, stream>>>(bufB, rp, esrc, bufA);
  fgemm_k<<<GG, 256, 0, stream>>>(bufA, w1r1t, w2r1t, bi1 + 2 * HID, sc2 + 2 * HID, bi2 + 2 * HID, d_out, HID, 0, 1);
}